// Round 1
// baseline (1640.438 us; speedup 1.0000x reference)
//
#include <hip/hip_runtime.h>
#include <hip/hip_bf16.h>
#include <math.h>

// ---------------------------------------------------------------------------
// Generalised gated MoE U-net, B=2048, E=4, W=10, fp32 throughout.
// Round 0: correctness-first implementation.
//   - conv: thread = (b, w, 2-row pixel pair), all 4 experts in regs,
//     c = blockIdx.y so weight loads are wave-uniform (scalar loads).
//   - gate: wave per row, float4 gw/nw loads, shfl reduce, atomic colsum.
//   - concat layers are virtual (two-pointer indexing).
// ---------------------------------------------------------------------------

constexpr int BATCH = 2048;

// ---------------- workspace layout (in floats) ----------------
constexpr size_t PADF    = 1024;                       // 4KB guard pads
constexpr size_t F_CONV1 = (size_t)BATCH * 10 * 784;   // 16,056,320
constexpr size_t F_XPAD  = (size_t)BATCH * 784;
constexpr size_t F_P1    = (size_t)BATCH * 10 * 196;
constexpr size_t F_CONV2 = F_P1;
constexpr size_t F_P2    = (size_t)BATCH * 10 * 49;
constexpr size_t F_CONV3 = (size_t)BATCH * 20 * 49;
constexpr size_t F_UP3   = (size_t)BATCH * 20 * 196;
constexpr size_t F_M4    = F_P1;
constexpr size_t F_UP4   = F_CONV1;
constexpr size_t F_M5    = F_CONV1;

constexpr size_t O_CONV1 = PADF;
constexpr size_t O_Z2    = O_CONV1 + F_CONV1 + PADF;
constexpr size_t O_XPAD  = O_Z2;
constexpr size_t O_P1    = O_XPAD + F_XPAD + PADF;
constexpr size_t O_CONV2 = O_P1 + F_P1 + PADF;
constexpr size_t O_P2    = O_CONV2 + F_CONV2 + PADF;
constexpr size_t O_CONV3 = O_P2 + F_P2 + PADF;
constexpr size_t O_UP3   = O_CONV3 + F_CONV3 + PADF;
constexpr size_t O_M4    = O_UP3 + F_UP3 + PADF;       // phase-2 zone end
// phase 3: xpad..up3 are dead; overlay up4/m5 there (m4 stays live past up4).
constexpr size_t O_UP4   = O_Z2;                        // < O_M4, no overlap
constexpr size_t O_M5    = O_Z2 + F_UP4 + PADF;         // overlays dead m4 later
constexpr size_t O_GRAW  = O_M5 + F_M5 + PADF;          // 5 x B x 4
constexpr size_t O_GATE  = O_GRAW + 5 * (size_t)BATCH * 4;
constexpr size_t O_CS    = O_GATE + 5 * (size_t)BATCH * 4;  // 5 x 64
constexpr size_t WS_FLOATS = O_CS + 5 * 64 + PADF;

__device__ __forceinline__ float softplusf(float z) {
    return fmaxf(z, 0.0f) + log1pf(expf(-fabsf(z)));
}

// ---------------- gate: g = xf@gw+gb, n=softplus(xf@nw+nb), graw=g+eps*n ----
template <int C1, int C2, int HW>
__global__ __launch_bounds__(256) void gate_compute(
    const float* __restrict__ x1, const float* __restrict__ x2,
    const float* __restrict__ gw, const float* __restrict__ gb,
    const float* __restrict__ nw, const float* __restrict__ nb,
    const float* __restrict__ eps,
    float* __restrict__ graw, float* __restrict__ colsum)
{
    constexpr int D = (C1 + C2) * HW;
    const int wave = threadIdx.x >> 6;
    const int lane = threadIdx.x & 63;
    const int b = blockIdx.x * 4 + wave;
    if (b >= BATCH) return;

    float ga0 = 0.f, ga1 = 0.f, ga2 = 0.f, ga3 = 0.f;
    float na0 = 0.f, na1 = 0.f, na2 = 0.f, na3 = 0.f;

    for (int d = lane; d < D; d += 64) {
        const int c = d / HW;
        const int s = d - c * HW;
        float val;
        if constexpr (C2 > 0) {
            val = (c < C1) ? x1[((size_t)b * C1 + c) * HW + s]
                           : x2[((size_t)b * C2 + (c - C1)) * HW + s];
        } else {
            val = x1[((size_t)b * C1 + c) * HW + s];
        }
        const float4 gv = ((const float4*)gw)[d];
        const float4 nv = ((const float4*)nw)[d];
        ga0 = fmaf(val, gv.x, ga0); ga1 = fmaf(val, gv.y, ga1);
        ga2 = fmaf(val, gv.z, ga2); ga3 = fmaf(val, gv.w, ga3);
        na0 = fmaf(val, nv.x, na0); na1 = fmaf(val, nv.y, na1);
        na2 = fmaf(val, nv.z, na2); na3 = fmaf(val, nv.w, na3);
    }
    #pragma unroll
    for (int m = 32; m >= 1; m >>= 1) {
        ga0 += __shfl_xor(ga0, m, 64); ga1 += __shfl_xor(ga1, m, 64);
        ga2 += __shfl_xor(ga2, m, 64); ga3 += __shfl_xor(ga3, m, 64);
        na0 += __shfl_xor(na0, m, 64); na1 += __shfl_xor(na1, m, 64);
        na2 += __shfl_xor(na2, m, 64); na3 += __shfl_xor(na3, m, 64);
    }
    if (lane == 0) {
        float ga[4] = {ga0, ga1, ga2, ga3};
        float na[4] = {na0, na1, na2, na3};
        #pragma unroll
        for (int e = 0; e < 4; ++e) {
            float g = ga[e] + gb[e] + eps[e] * softplusf(na[e] + nb[e]);
            graw[b * 4 + e] = g;
            atomicAdd(&colsum[e], g);
        }
    }
}

// ---------------- gate finalize: top-k mask (by colsum) + masked softmax ----
__global__ __launch_bounds__(256) void gate_finalize(
    const float* __restrict__ graw, const float* __restrict__ colsum,
    const int* __restrict__ kp, float* __restrict__ gate)
{
    const int b = blockIdx.x * 256 + threadIdx.x;
    if (b >= BATCH) return;
    int k = kp[0];
    k = (k < 1) ? 1 : (k > 4 ? 4 : k);

    float cs[4];
    bool sel[4] = {false, false, false, false};
    #pragma unroll
    for (int e = 0; e < 4; ++e) cs[e] = colsum[e];
    for (int it = 0; it < k; ++it) {
        int bi = 0; float bv = -INFINITY;
        #pragma unroll
        for (int e = 0; e < 4; ++e)
            if (!sel[e] && cs[e] > bv) { bv = cs[e]; bi = e; }
        sel[bi] = true;
    }
    float g[4];
    #pragma unroll
    for (int e = 0; e < 4; ++e) {
        float v = graw[b * 4 + e];
        g[e] = sel[e] ? v : 0.0f;   // zero BEFORE softmax (as in reference)
    }
    float m = fmaxf(fmaxf(g[0], g[1]), fmaxf(g[2], g[3]));
    float e0 = expf(g[0] - m), e1 = expf(g[1] - m);
    float e2 = expf(g[2] - m), e3 = expf(g[3] - m);
    float inv = 1.0f / (e0 + e1 + e2 + e3);
    gate[b * 4 + 0] = e0 * inv; gate[b * 4 + 1] = e1 * inv;
    gate[b * 4 + 2] = e2 * inv; gate[b * 4 + 3] = e3 * inv;
}

// ---------------- MoE conv 3x3 SAME + relu + gate-weighted expert sum ------
// out[b,c,h,w] = sum_e gate[b,e] * relu(sum_ci,kh,kw x[b,ci,..]*cw[e,c,ci,..] + cb[e,c])
// thread = (b, w, row pair h0/h0+1); c = blockIdx.y (uniform -> scalar weights)
template <int CIN1, int CIN2, int COUT, int H, int W>
__global__ __launch_bounds__(256) void moe_conv(
    const float* __restrict__ x1, const float* __restrict__ x2,
    const float* __restrict__ cw, const float* __restrict__ cb,
    const float* __restrict__ gate, float* __restrict__ out)
{
    constexpr int CIN = CIN1 + CIN2;
    constexpr int H2 = (H + 1) / 2;
    const int c = blockIdx.y;
    const int t = blockIdx.x * 256 + threadIdx.x;
    constexpr int TOTAL = BATCH * H2 * W;
    if (t >= TOTAL) return;
    const int b  = t / (H2 * W);
    const int r  = t - b * (H2 * W);
    const int h2 = r / W;
    const int w  = r - h2 * W;
    const int h0 = 2 * h2;

    float acc0[4], acc1[4];
    #pragma unroll
    for (int e = 0; e < 4; ++e) {
        float bv = cb[e * COUT + c];
        acc0[e] = bv; acc1[e] = bv;
    }

    // tap validity masks and base offsets (independent of ci)
    float msk[4][3];
    int   base[4];
    #pragma unroll
    for (int rr = 0; rr < 4; ++rr) {
        const int y = h0 - 1 + rr;
        const float my = (y >= 0 && y < H) ? 1.0f : 0.0f;
        base[rr] = y * W + (w - 1);       // may be out of range; buffers padded
        #pragma unroll
        for (int dc = 0; dc < 3; ++dc) {
            const int xx = w - 1 + dc;
            msk[rr][dc] = ((xx >= 0 && xx < W) ? 1.0f : 0.0f) * my;
        }
    }

    const float* xb1 = x1 + (size_t)b * CIN1 * (H * W);
    const float* xb2 = (CIN2 > 0) ? (x2 + (size_t)b * CIN2 * (H * W)) : nullptr;

    for (int ci = 0; ci < CIN; ++ci) {
        const float* xp;
        if constexpr (CIN2 > 0) {
            xp = (ci < CIN1) ? (xb1 + ci * (H * W)) : (xb2 + (ci - CIN1) * (H * W));
        } else {
            xp = xb1 + ci * (H * W);
        }
        float v[4][3];
        #pragma unroll
        for (int rr = 0; rr < 4; ++rr) {
            #pragma unroll
            for (int dc = 0; dc < 3; ++dc) {
                v[rr][dc] = xp[base[rr] + dc] * msk[rr][dc];
            }
        }
        #pragma unroll
        for (int e = 0; e < 4; ++e) {
            const float* wp = cw + (((size_t)(e * COUT + c) * CIN + ci) * 9);
            #pragma unroll
            for (int kh = 0; kh < 3; ++kh) {
                #pragma unroll
                for (int kw = 0; kw < 3; ++kw) {
                    const float wv = wp[kh * 3 + kw];   // wave-uniform -> s_load
                    acc0[e] = fmaf(v[kh][kw],     wv, acc0[e]);
                    acc1[e] = fmaf(v[kh + 1][kw], wv, acc1[e]);
                }
            }
        }
    }

    const float* gp = gate + b * 4;
    const float g0 = gp[0], g1 = gp[1], g2 = gp[2], g3 = gp[3];
    float r0 = g0 * fmaxf(acc0[0], 0.f) + g1 * fmaxf(acc0[1], 0.f)
             + g2 * fmaxf(acc0[2], 0.f) + g3 * fmaxf(acc0[3], 0.f);
    float r1 = g0 * fmaxf(acc1[0], 0.f) + g1 * fmaxf(acc1[1], 0.f)
             + g2 * fmaxf(acc1[2], 0.f) + g3 * fmaxf(acc1[3], 0.f);
    float* op = out + ((size_t)b * COUT + c) * (H * W) + h0 * W + w;
    op[0] = r0;
    if (h0 + 1 < H) op[W] = r1;
}

// ---------------- 2x2 maxpool stride 2 ----------------
template <int N>
__global__ __launch_bounds__(256) void maxpool2(
    const float* __restrict__ in, float* __restrict__ out, int BC)
{
    constexpr int N2 = N / 2;
    const int idx = blockIdx.x * 256 + threadIdx.x;
    const int total = BC * N2 * N2;
    if (idx >= total) return;
    const int j = idx % N2;
    int tmp = idx / N2;
    const int i = tmp % N2;
    const int bc = tmp / N2;
    const float* p = in + (size_t)bc * N * N + (2 * i) * N + 2 * j;
    out[idx] = fmaxf(fmaxf(p[0], p[1]), fmaxf(p[N], p[N + 1]));
}

// ---------------- bilinear x2 upsample, align_corners=True ----------------
template <int N>
__global__ __launch_bounds__(256) void upsample2(
    const float* __restrict__ in, float* __restrict__ out, int BC)
{
    constexpr int M = 2 * N;
    const int idx = blockIdx.x * 256 + threadIdx.x;
    const int total = BC * M * M;
    if (idx >= total) return;
    const int x = idx % M;
    int tmp = idx / M;
    const int y = tmp % M;
    const int bc = tmp / M;
    const float scale = (float)((double)(N - 1) / (double)(M - 1));
    const float cy = (float)y * scale;
    const float cx = (float)x * scale;
    const int iy0 = (int)floorf(cy);
    const int ix0 = (int)floorf(cx);
    const int iy1 = min(iy0 + 1, N - 1);
    const int ix1 = min(ix0 + 1, N - 1);
    const float wy = cy - (float)iy0;
    const float wx = cx - (float)ix0;
    const float* p = in + (size_t)bc * N * N;
    const float v00 = p[iy0 * N + ix0], v01 = p[iy0 * N + ix1];
    const float v10 = p[iy1 * N + ix0], v11 = p[iy1 * N + ix1];
    const float a0 = v00 * (1.0f - wy) + v10 * wy;   // upsample H first (ref order)
    const float a1 = v01 * (1.0f - wy) + v11 * wy;
    out[idx] = a0 * (1.0f - wx) + a1 * wx;
}

// ---------------- final 1x1 conv ----------------
__global__ __launch_bounds__(256) void final1x1(
    const float* __restrict__ h, const float* __restrict__ wl,
    const float* __restrict__ bl, float* __restrict__ out)
{
    const int idx = blockIdx.x * 256 + threadIdx.x;
    const int total = BATCH * 784;
    if (idx >= total) return;
    const int s = idx % 784;
    const int b = idx / 784;
    float acc = bl[0];
    #pragma unroll
    for (int c = 0; c < 10; ++c)
        acc += h[((size_t)b * 10 + c) * 784 + s] * wl[c];
    out[idx] = acc;
}

// ---------------------------------------------------------------------------
extern "C" void kernel_launch(void* const* d_in, const int* in_sizes, int n_in,
                              void* d_out, int out_size, void* d_ws, size_t ws_size,
                              hipStream_t stream)
{
    const float* x = (const float*)d_in[0];
    // per-layer params, dict order: cw,cb,gw,gb,nw,nb,eps
    const float* cw[5]; const float* cb[5]; const float* gw[5]; const float* gb[5];
    const float* nw[5]; const float* nb[5]; const float* epsv[5];
    for (int l = 0; l < 5; ++l) {
        cw[l]   = (const float*)d_in[1 + 7 * l + 0];
        cb[l]   = (const float*)d_in[1 + 7 * l + 1];
        gw[l]   = (const float*)d_in[1 + 7 * l + 2];
        gb[l]   = (const float*)d_in[1 + 7 * l + 3];
        nw[l]   = (const float*)d_in[1 + 7 * l + 4];
        nb[l]   = (const float*)d_in[1 + 7 * l + 5];
        epsv[l] = (const float*)d_in[1 + 7 * l + 6];
    }
    const float* wlast = (const float*)d_in[36];
    const float* blast = (const float*)d_in[37];
    const int*   kp    = (const int*)d_in[38];
    float* out = (float*)d_out;
    float* ws  = (float*)d_ws;

    float* conv1 = ws + O_CONV1;
    float* xpad  = ws + O_XPAD;
    float* p1    = ws + O_P1;
    float* conv2 = ws + O_CONV2;
    float* p2    = ws + O_P2;
    float* conv3 = ws + O_CONV3;
    float* up3   = ws + O_UP3;
    float* m4    = ws + O_M4;
    float* up4   = ws + O_UP4;
    float* m5    = ws + O_M5;
    float* graw[5]; float* gatep[5]; float* cs[5];
    for (int l = 0; l < 5; ++l) {
        graw[l]  = ws + O_GRAW + (size_t)l * BATCH * 4;
        gatep[l] = ws + O_GATE + (size_t)l * BATCH * 4;
        cs[l]    = ws + O_CS + (size_t)l * 64;
    }

    // zero the 5 colsum slots (re-poisoned to 0xAA before every launch)
    hipMemsetAsync(ws + O_CS, 0, 5 * 64 * sizeof(float), stream);
    // padded copy of x so border taps of moe1 never read before the buffer
    hipMemcpyAsync(xpad, x, (size_t)BATCH * 784 * sizeof(float),
                   hipMemcpyDeviceToDevice, stream);

    const int GB = BATCH / 4;  // gate_compute blocks (wave per row)
    #define CDIV(a) (((a) + 255) / 256)

    // ---- layer 1: x [B,1,28,28] -> conv1 [B,10,28,28]
    gate_compute<1, 0, 784><<<GB, 256, 0, stream>>>(
        x, nullptr, gw[0], gb[0], nw[0], nb[0], epsv[0], graw[0], cs[0]);
    gate_finalize<<<CDIV(BATCH), 256, 0, stream>>>(graw[0], cs[0], kp, gatep[0]);
    moe_conv<1, 0, 10, 28, 28><<<dim3(CDIV(BATCH * 14 * 28), 10), 256, 0, stream>>>(
        xpad, nullptr, cw[0], cb[0], gatep[0], conv1);
    maxpool2<28><<<CDIV(BATCH * 10 * 196), 256, 0, stream>>>(conv1, p1, BATCH * 10);

    // ---- layer 2: p1 [B,10,14,14] -> conv2 [B,10,14,14]
    gate_compute<10, 0, 196><<<GB, 256, 0, stream>>>(
        p1, nullptr, gw[1], gb[1], nw[1], nb[1], epsv[1], graw[1], cs[1]);
    gate_finalize<<<CDIV(BATCH), 256, 0, stream>>>(graw[1], cs[1], kp, gatep[1]);
    moe_conv<10, 0, 10, 14, 14><<<dim3(CDIV(BATCH * 7 * 14), 10), 256, 0, stream>>>(
        p1, nullptr, cw[1], cb[1], gatep[1], conv2);
    maxpool2<14><<<CDIV(BATCH * 10 * 49), 256, 0, stream>>>(conv2, p2, BATCH * 10);

    // ---- layer 3: p2 [B,10,7,7] -> conv3 [B,20,7,7]
    gate_compute<10, 0, 49><<<GB, 256, 0, stream>>>(
        p2, nullptr, gw[2], gb[2], nw[2], nb[2], epsv[2], graw[2], cs[2]);
    gate_finalize<<<CDIV(BATCH), 256, 0, stream>>>(graw[2], cs[2], kp, gatep[2]);
    moe_conv<10, 0, 20, 7, 7><<<dim3(CDIV(BATCH * 4 * 7), 20), 256, 0, stream>>>(
        p2, nullptr, cw[2], cb[2], gatep[2], conv3);
    upsample2<7><<<CDIV(BATCH * 20 * 196), 256, 0, stream>>>(conv3, up3, BATCH * 20);

    // ---- layer 4: virtual concat [up3(20ch) | conv2(10ch)] -> m4 [B,10,14,14]
    gate_compute<20, 10, 196><<<GB, 256, 0, stream>>>(
        up3, conv2, gw[3], gb[3], nw[3], nb[3], epsv[3], graw[3], cs[3]);
    gate_finalize<<<CDIV(BATCH), 256, 0, stream>>>(graw[3], cs[3], kp, gatep[3]);
    moe_conv<20, 10, 10, 14, 14><<<dim3(CDIV(BATCH * 7 * 14), 10), 256, 0, stream>>>(
        up3, conv2, cw[3], cb[3], gatep[3], m4);
    upsample2<14><<<CDIV(BATCH * 10 * 784), 256, 0, stream>>>(m4, up4, BATCH * 10);

    // ---- layer 5: virtual concat [up4(10ch) | conv1(10ch)] -> m5 [B,10,28,28]
    gate_compute<10, 10, 784><<<GB, 256, 0, stream>>>(
        up4, conv1, gw[4], gb[4], nw[4], nb[4], epsv[4], graw[4], cs[4]);
    gate_finalize<<<CDIV(BATCH), 256, 0, stream>>>(graw[4], cs[4], kp, gatep[4]);
    moe_conv<10, 10, 10, 28, 28><<<dim3(CDIV(BATCH * 14 * 28), 10), 256, 0, stream>>>(
        up4, conv1, cw[4], cb[4], gatep[4], m5);

    // ---- final 1x1
    final1x1<<<CDIV(BATCH * 784), 256, 0, stream>>>(m5, wlast, blast, out);
    #undef CDIV
}